// Round 3
// baseline (730.579 us; speedup 1.0000x reference)
//
#include <hip/hip_runtime.h>

// ---------- fp32 -> bf16 (round-to-nearest-even) ----------
__device__ __forceinline__ unsigned short f2bf(float f) {
    union { float f; unsigned int i; } v;
    v.f = f;
    unsigned int x = v.i;
    return (unsigned short)((x + 0x7fffu + ((x >> 16) & 1u)) >> 16);
}

typedef short bf16x8 __attribute__((ext_vector_type(8)));
typedef float f32x4 __attribute__((ext_vector_type(4)));

// ---------- CSR build ----------
__global__ void zero_int_kernel(int* __restrict__ p, int n) {
    int i = blockIdx.x * blockDim.x + threadIdx.x;
    if (i < n) p[i] = 0;
}

__global__ void hist_kernel(const int* __restrict__ dst, int* __restrict__ deg, int ne) {
    int e = blockIdx.x * blockDim.x + threadIdx.x;
    if (e < ne) atomicAdd(&deg[dst[e]], 1);
}

__global__ __launch_bounds__(1024) void scan_local_kernel(
    const int* __restrict__ deg, int* __restrict__ offs, int* __restrict__ bsum, int n)
{
    __shared__ int sh[1024];
    int t = threadIdx.x;
    int i = blockIdx.x * 1024 + t;
    int v = (i < n) ? deg[i] : 0;
    sh[t] = v;
    __syncthreads();
    int acc = v;
    for (int off = 1; off < 1024; off <<= 1) {
        int y = (t >= off) ? sh[t - off] : 0;
        __syncthreads();
        acc += y;
        sh[t] = acc;
        __syncthreads();
    }
    if (i < n) offs[i] = acc - v;  // exclusive within block
    if (t == 1023) bsum[blockIdx.x] = acc;
}

__global__ __launch_bounds__(128) void scan_totals_kernel(
    int* __restrict__ bsum, int* __restrict__ offs, int nb, int n)
{
    __shared__ int sh[128];
    int t = threadIdx.x;
    int v = (t < nb) ? bsum[t] : 0;
    sh[t] = v;
    __syncthreads();
    int acc = v;
    for (int off = 1; off < 128; off <<= 1) {
        int y = (t >= off) ? sh[t - off] : 0;
        __syncthreads();
        acc += y;
        sh[t] = acc;
        __syncthreads();
    }
    if (t < nb) bsum[t] = acc - v;   // exclusive block offsets, in place
    if (t == 127) offs[n] = acc;     // grand total == NE
}

__global__ __launch_bounds__(1024) void scan_finalize_kernel(
    int* __restrict__ offs, const int* __restrict__ bsum, int* __restrict__ cursor, int n)
{
    int i = blockIdx.x * 1024 + threadIdx.x;
    if (i < n) {
        int o = offs[i] + bsum[i >> 10];
        offs[i] = o;
        cursor[i] = o;
    }
}

__global__ void fill_csr_kernel(const int* __restrict__ src, const int* __restrict__ dst,
                                int* __restrict__ cursor, int* __restrict__ csr, int ne)
{
    int e = blockIdx.x * blockDim.x + threadIdx.x;
    if (e < ne) {
        int d = dst[e];
        int pos = atomicAdd(&cursor[d], 1);
        csr[pos] = src[e];
    }
}

// ---------- W fp32 -> bf16 (4 x 128x128) ----------
__global__ void wconv_kernel(const float* __restrict__ W1, const float* __restrict__ W2,
                             const float* __restrict__ W3, const float* __restrict__ W4,
                             unsigned short* __restrict__ Wb)
{
    int i = blockIdx.x * 256 + threadIdx.x;  // 0..65535
    const float* src = (i < 16384) ? W1 : (i < 32768) ? W2 : (i < 49152) ? W3 : W4;
    Wb[i] = f2bf(src[i & 16383]);
}

// ---------- Fused gather + 4-panel bf16 MFMA GEMM + fp32 epilogue ----------
// Per block of 64 nodes:
//   g[r] = sum_{e in CSR[r]} x[src[e]]   (fp32 accumulate, rounded to bf16 LDS)
//   P1 = x*W1^T ; Pk = g*Wk^T
//   out = sigmoid(2*P3+2*deg*b3 + 2*P4+2*deg*b4) * (2*P2+2*deg*b2) + P1 + b1
__global__ __launch_bounds__(256) void fused_kernel(
    const float* __restrict__ x,
    const int* __restrict__ offs, const int* __restrict__ csr,
    const int* __restrict__ deg,
    const unsigned short* __restrict__ Wb,
    const float* __restrict__ B1, const float* __restrict__ B2,
    const float* __restrict__ B3, const float* __restrict__ B4,
    float* __restrict__ out, int M)
{
    __shared__ unsigned short x_lds[64 * 136];
    __shared__ unsigned short g_lds[64 * 136];

    const int t = threadIdx.x;
    const int wave = t >> 6;
    const int lane = t & 63;
    const int ln = lane & 15;
    const int quad = lane >> 4;
    const int row0 = blockIdx.x * 64;

    // ---- stage x tile (64 rows x 128 fp32 -> bf16 LDS) ----
#pragma unroll
    for (int i = 0; i < 8; ++i) {
        int c = i * 256 + t;          // 0..2047 float4-chunks
        int row = c >> 5;             // 0..63
        int koff = (c & 31) * 4;      // 0..124
        int grow = row0 + row;
        if (grow > M - 1) grow = M - 1;
        float4 v = *(const float4*)(x + (size_t)grow * 128 + koff);
        unsigned p0 = (unsigned)f2bf(v.x) | ((unsigned)f2bf(v.y) << 16);
        unsigned p1 = (unsigned)f2bf(v.z) | ((unsigned)f2bf(v.w) << 16);
        *(unsigned*)&x_lds[row * 136 + koff]     = p0;
        *(unsigned*)&x_lds[row * 136 + koff + 2] = p1;
    }

    // ---- gather: wave handles rows [wave*16, wave*16+16); lane covers 2 features ----
    for (int rr = 0; rr < 16; ++rr) {
        const int lrow = wave * 16 + rr;
        const int row = row0 + lrow;
        float s00 = 0.f, s01 = 0.f, s10 = 0.f, s11 = 0.f;
        float s20 = 0.f, s21 = 0.f, s30 = 0.f, s31 = 0.f;
        if (row < M) {
            int e  = offs[row];
            int e1 = offs[row + 1];
            for (; e + 3 < e1; e += 4) {
                unsigned sa = (unsigned)csr[e];
                unsigned sb = (unsigned)csr[e + 1];
                unsigned sc = (unsigned)csr[e + 2];
                unsigned sd = (unsigned)csr[e + 3];
                if (sa >= (unsigned)M) sa = 0;   // defensive clamp
                if (sb >= (unsigned)M) sb = 0;
                if (sc >= (unsigned)M) sc = 0;
                if (sd >= (unsigned)M) sd = 0;
                float2 va = *(const float2*)(x + (size_t)sa * 128 + lane * 2);
                float2 vb = *(const float2*)(x + (size_t)sb * 128 + lane * 2);
                float2 vc = *(const float2*)(x + (size_t)sc * 128 + lane * 2);
                float2 vd = *(const float2*)(x + (size_t)sd * 128 + lane * 2);
                s00 += va.x; s01 += va.y;
                s10 += vb.x; s11 += vb.y;
                s20 += vc.x; s21 += vc.y;
                s30 += vd.x; s31 += vd.y;
            }
            for (; e < e1; ++e) {
                unsigned sa = (unsigned)csr[e];
                if (sa >= (unsigned)M) sa = 0;
                float2 va = *(const float2*)(x + (size_t)sa * 128 + lane * 2);
                s00 += va.x; s01 += va.y;
            }
        }
        float g0 = (s00 + s10) + (s20 + s30);
        float g1 = (s01 + s11) + (s21 + s31);
        unsigned pk = (unsigned)f2bf(g0) | ((unsigned)f2bf(g1) << 16);
        *(unsigned*)&g_lds[lrow * 136 + lane * 2] = pk;
    }
    __syncthreads();

    // ---- 4-panel GEMM: wave owns cols [wave*32, wave*32+32) ----
    f32x4 acc[4][4][2];  // [panel][row-tile][col-tile]
#pragma unroll
    for (int p = 0; p < 4; ++p)
#pragma unroll
        for (int rt = 0; rt < 4; ++rt)
#pragma unroll
            for (int c = 0; c < 2; ++c) {
                acc[p][rt][c][0] = 0.f; acc[p][rt][c][1] = 0.f;
                acc[p][rt][c][2] = 0.f; acc[p][rt][c][3] = 0.f;
            }

#pragma unroll
    for (int kk = 0; kk < 4; ++kk) {
        bf16x8 ax[4], ag[4];
#pragma unroll
        for (int rt = 0; rt < 4; ++rt) {
            ax[rt] = *(const bf16x8*)&x_lds[(rt * 16 + ln) * 136 + kk * 32 + quad * 8];
            ag[rt] = *(const bf16x8*)&g_lds[(rt * 16 + ln) * 136 + kk * 32 + quad * 8];
        }
#pragma unroll
        for (int p = 0; p < 4; ++p) {
#pragma unroll
            for (int c = 0; c < 2; ++c) {
                int col = wave * 32 + c * 16 + ln;
                bf16x8 bw = *(const bf16x8*)(Wb + (size_t)p * 16384 + (size_t)col * 128 + kk * 32 + quad * 8);
#pragma unroll
                for (int rt = 0; rt < 4; ++rt) {
                    acc[p][rt][c] = __builtin_amdgcn_mfma_f32_16x16x32_bf16(
                        (p == 0) ? ax[rt] : ag[rt], bw, acc[p][rt][c], 0, 0, 0);
                }
            }
        }
    }

    // ---- epilogue (fp32) ----
#pragma unroll
    for (int rt = 0; rt < 4; ++rt) {
#pragma unroll
        for (int i = 0; i < 4; ++i) {
            int row = row0 + rt * 16 + quad * 4 + i;
            if (row < M) {
                float dg = (float)deg[row];
#pragma unroll
                for (int c = 0; c < 2; ++c) {
                    int col = wave * 32 + c * 16 + ln;
                    float p1 = acc[0][rt][c][i] + B1[col];
                    float h2 = 2.f * acc[1][rt][c][i] + 2.f * dg * B2[col];
                    float h3 = 2.f * acc[2][rt][c][i] + 2.f * dg * B3[col];
                    float h4 = 2.f * acc[3][rt][c][i] + 2.f * dg * B4[col];
                    float z = h3 + h4;
                    float g = 1.f / (1.f + __expf(-z));
                    out[(size_t)row * 128 + col] = g * h2 + p1;
                }
            }
        }
    }
}

extern "C" void kernel_launch(void* const* d_in, const int* in_sizes, int n_in,
                              void* d_out, int out_size, void* d_ws, size_t ws_size,
                              hipStream_t stream) {
    const float* x  = (const float*)d_in[0];
    const int* eidx = (const int*)d_in[1];
    const float* W1 = (const float*)d_in[2];
    const float* B1 = (const float*)d_in[3];
    const float* W2 = (const float*)d_in[4];
    const float* B2 = (const float*)d_in[5];
    const float* W3 = (const float*)d_in[6];
    const float* B3 = (const float*)d_in[7];
    const float* W4 = (const float*)d_in[8];
    const float* B4 = (const float*)d_in[9];
    float* out      = (float*)d_out;

    const int M  = in_sizes[0] / 128;   // 100000 nodes
    const int NE = in_sizes[1] / 2;     // 1600000 edges
    const int* src = eidx;
    const int* dst = eidx + NE;

    // workspace layout (~7.8 MB total)
    char* ws = (char*)d_ws;
    size_t off = 0;
    auto take = [&](size_t bytes) -> char* {
        char* p = ws + off;
        off = (off + bytes + 127) & ~(size_t)127;
        return p;
    };
    unsigned short* Wb = (unsigned short*)take(4 * 16384 * 2);
    int* deg    = (int*)take((size_t)M * 4);
    int* offs   = (int*)take((size_t)(M + 1) * 4);
    int* cursor = (int*)take((size_t)M * 4);
    int* bsum   = (int*)take(128 * 4);
    int* csr    = (int*)take((size_t)NE * 4);
    (void)ws_size;

    const int nbScan = (M + 1023) / 1024;

    zero_int_kernel<<<(M + 255) / 256, 256, 0, stream>>>(deg, M);
    wconv_kernel<<<256, 256, 0, stream>>>(W1, W2, W3, W4, Wb);
    hist_kernel<<<(NE + 255) / 256, 256, 0, stream>>>(dst, deg, NE);
    scan_local_kernel<<<nbScan, 1024, 0, stream>>>(deg, offs, bsum, M);
    scan_totals_kernel<<<1, 128, 0, stream>>>(bsum, offs, nbScan, M);
    scan_finalize_kernel<<<nbScan, 1024, 0, stream>>>(offs, bsum, cursor, M);
    fill_csr_kernel<<<(NE + 255) / 256, 256, 0, stream>>>(src, dst, cursor, csr, NE);
    fused_kernel<<<(M + 63) / 64, 256, 0, stream>>>(x, offs, csr, deg, Wb,
                                                    B1, B2, B3, B4, out, M);
}

// Round 4
// 672.329 us; speedup vs baseline: 1.0866x; 1.0866x over previous
//
#include <hip/hip_runtime.h>

// ---------- fp32 <-> bf16 helpers ----------
__device__ __forceinline__ float bf2f(unsigned short u) {
    union { unsigned int i; float f; } v;
    v.i = ((unsigned int)u) << 16;
    return v.f;
}
__device__ __forceinline__ unsigned short f2bf(float f) {
    union { float f; unsigned int i; } v;
    v.f = f;
    unsigned int x = v.i;
    return (unsigned short)((x + 0x7fffu + ((x >> 16) & 1u)) >> 16);
}

typedef short bf16x8 __attribute__((ext_vector_type(8)));
typedef float f32x4 __attribute__((ext_vector_type(4)));

// ---------- prep: zero deg, x fp32->bf16, W panels -> bf16 (W1, W2, W3+W4) ----------
__global__ void prep_kernel(const float* __restrict__ x,
                            const float* __restrict__ W1, const float* __restrict__ W2,
                            const float* __restrict__ W3, const float* __restrict__ W4,
                            unsigned short* __restrict__ xb, unsigned short* __restrict__ Wb,
                            int* __restrict__ deg, int M, int nx4)
{
    int i = blockIdx.x * 256 + threadIdx.x;
    if (i < nx4) {
        float4 v = ((const float4*)x)[i];
        unsigned lo = (unsigned)f2bf(v.x) | ((unsigned)f2bf(v.y) << 16);
        unsigned hi = (unsigned)f2bf(v.z) | ((unsigned)f2bf(v.w) << 16);
        uint2 p; p.x = lo; p.y = hi;
        *(uint2*)(xb + (size_t)i * 4) = p;
    }
    if (i < M) deg[i] = 0;
    if (i < 16384) {
        Wb[i]         = f2bf(W1[i]);
        Wb[16384 + i] = f2bf(W2[i]);
        Wb[32768 + i] = f2bf(W3[i] + W4[i]);
    }
}

// ---------- CSR build ----------
__global__ void hist_kernel(const int* __restrict__ dst, int* __restrict__ deg, int ne) {
    int e = blockIdx.x * blockDim.x + threadIdx.x;
    if (e < ne) atomicAdd(&deg[dst[e]], 1);
}

// single-block two-pass scan: offs (exclusive) + cursor copy + offs[n] = total
__global__ __launch_bounds__(1024) void scan_kernel(
    const int* __restrict__ deg, int* __restrict__ offs, int* __restrict__ cursor,
    int n, int ch)
{
    __shared__ int sh[1024];
    const int t = threadIdx.x;
    const long base = (long)t * ch;
    int total = 0;
    for (int i = 0; i < ch; ++i) {
        long idx = base + i;
        if (idx < n) total += deg[idx];
    }
    sh[t] = total;
    __syncthreads();
    int acc = total;
    for (int off = 1; off < 1024; off <<= 1) {
        int y = (t >= off) ? sh[t - off] : 0;
        __syncthreads();
        acc += y;
        sh[t] = acc;
        __syncthreads();
    }
    int run = acc - total;  // exclusive prefix of this thread's chunk
    for (int i = 0; i < ch; ++i) {
        long idx = base + i;
        if (idx < n) {
            offs[idx] = run;
            cursor[idx] = run;
            run += deg[idx];
        }
    }
    if (t == 1023) offs[n] = acc;  // grand total == NE
}

__global__ void fill_csr_kernel(const int* __restrict__ src, const int* __restrict__ dst,
                                int* __restrict__ cursor, int* __restrict__ csr, int ne)
{
    int e = blockIdx.x * blockDim.x + threadIdx.x;
    if (e < ne) {
        int d = dst[e];
        int pos = atomicAdd(&cursor[d], 1);
        csr[pos] = src[e];
    }
}

// ---------- gather: one wave per node, 8-deep masked unroll, bf16 out ----------
template<bool BF16SRC>
__global__ __launch_bounds__(256) void gather_kernel(
    const void* __restrict__ xsrc, const int* __restrict__ offs,
    const int* __restrict__ csr, unsigned short* __restrict__ gb, int M)
{
    const int wave = threadIdx.x >> 6;
    const int lane = threadIdx.x & 63;
    const int node = blockIdx.x * 4 + wave;
    if (node >= M) return;
    const int e0 = offs[node];
    const int e1 = offs[node + 1];

    float s0 = 0.f, s1 = 0.f, t0 = 0.f, t1 = 0.f;
    for (int e = e0; e < e1; e += 8) {
        int id[8];
        float m[8];
#pragma unroll
        for (int j = 0; j < 8; ++j) {
            int ee = e + j;
            bool ok = ee < e1;
            id[j] = csr[ok ? ee : e1 - 1];
            m[j] = ok ? 1.f : 0.f;
        }
#pragma unroll
        for (int j = 0; j < 8; ++j) {
            float lo, hi;
            if (BF16SRC) {
                unsigned v = *(const unsigned*)((const unsigned short*)xsrc +
                                                (size_t)id[j] * 128 + lane * 2);
                lo = bf2f((unsigned short)(v & 0xffffu));
                hi = bf2f((unsigned short)(v >> 16));
            } else {
                float2 v = *(const float2*)((const float*)xsrc +
                                            (size_t)id[j] * 128 + lane * 2);
                lo = v.x;
                hi = v.y;
            }
            if (j & 1) { t0 += m[j] * lo; t1 += m[j] * hi; }
            else       { s0 += m[j] * lo; s1 += m[j] * hi; }
        }
    }
    unsigned pk = (unsigned)f2bf(s0 + t0) | ((unsigned)f2bf(s1 + t1) << 16);
    *(unsigned*)(gb + (size_t)node * 128 + lane * 2) = pk;
}

// ---------- 3-panel bf16 MFMA GEMM + fp32 epilogue ----------
// P1 = x*W1^T ; P2 = g*W2^T ; P34 = g*(W3+W4)^T
// out = sigmoid(2*(P34 + d*(b3+b4))) * (2*(P2 + d*b2)) + P1 + b1
template<bool XBF16>
__global__ __launch_bounds__(256) void gemm_kernel(
    const void* __restrict__ xsrc, const unsigned short* __restrict__ gb,
    const int* __restrict__ deg, const unsigned short* __restrict__ Wb,
    const float* __restrict__ B1, const float* __restrict__ B2,
    const float* __restrict__ B3, const float* __restrict__ B4,
    float* __restrict__ out, int M)
{
    __shared__ unsigned short x_lds[64 * 136];
    __shared__ unsigned short g_lds[64 * 136];

    const int t = threadIdx.x;
    const int wave = t >> 6;
    const int lane = t & 63;
    const int ln = lane & 15;
    const int quad = lane >> 4;
    const int row0 = blockIdx.x * 64;

    // ---- stage x tile ----
    if (XBF16) {
        const unsigned short* xb = (const unsigned short*)xsrc;
#pragma unroll
        for (int i = 0; i < 4; ++i) {
            int c = i * 256 + t;          // 1024 chunks of 16B
            int row = c >> 4;
            int koff = (c & 15) * 8;
            int grow = row0 + row;
            if (grow > M - 1) grow = M - 1;
            *(uint4*)&x_lds[row * 136 + koff] =
                *(const uint4*)(xb + (size_t)grow * 128 + koff);
        }
    } else {
        const float* xf = (const float*)xsrc;
#pragma unroll
        for (int i = 0; i < 8; ++i) {
            int c = i * 256 + t;          // 2048 chunks of float4
            int row = c >> 5;
            int koff = (c & 31) * 4;
            int grow = row0 + row;
            if (grow > M - 1) grow = M - 1;
            float4 v = *(const float4*)(xf + (size_t)grow * 128 + koff);
            unsigned p0 = (unsigned)f2bf(v.x) | ((unsigned)f2bf(v.y) << 16);
            unsigned p1 = (unsigned)f2bf(v.z) | ((unsigned)f2bf(v.w) << 16);
            *(unsigned*)&x_lds[row * 136 + koff]     = p0;
            *(unsigned*)&x_lds[row * 136 + koff + 2] = p1;
        }
    }
    // ---- stage g tile ----
#pragma unroll
    for (int i = 0; i < 4; ++i) {
        int c = i * 256 + t;
        int row = c >> 4;
        int koff = (c & 15) * 8;
        int grow = row0 + row;
        if (grow > M - 1) grow = M - 1;
        *(uint4*)&g_lds[row * 136 + koff] =
            *(const uint4*)(gb + (size_t)grow * 128 + koff);
    }
    __syncthreads();

    // ---- 3-panel GEMM: wave owns cols [wave*32, wave*32+32) ----
    f32x4 acc[3][4][2];
#pragma unroll
    for (int p = 0; p < 3; ++p)
#pragma unroll
        for (int rt = 0; rt < 4; ++rt)
#pragma unroll
            for (int c = 0; c < 2; ++c) {
                acc[p][rt][c][0] = 0.f; acc[p][rt][c][1] = 0.f;
                acc[p][rt][c][2] = 0.f; acc[p][rt][c][3] = 0.f;
            }

#pragma unroll
    for (int kk = 0; kk < 4; ++kk) {
        bf16x8 ax[4], ag[4];
#pragma unroll
        for (int rt = 0; rt < 4; ++rt) {
            ax[rt] = *(const bf16x8*)&x_lds[(rt * 16 + ln) * 136 + kk * 32 + quad * 8];
            ag[rt] = *(const bf16x8*)&g_lds[(rt * 16 + ln) * 136 + kk * 32 + quad * 8];
        }
#pragma unroll
        for (int p = 0; p < 3; ++p) {
#pragma unroll
            for (int c = 0; c < 2; ++c) {
                int col = wave * 32 + c * 16 + ln;
                bf16x8 bw = *(const bf16x8*)(Wb + (size_t)p * 16384 +
                                             (size_t)col * 128 + kk * 32 + quad * 8);
#pragma unroll
                for (int rt = 0; rt < 4; ++rt) {
                    acc[p][rt][c] = __builtin_amdgcn_mfma_f32_16x16x32_bf16(
                        (p == 0) ? ax[rt] : ag[rt], bw, acc[p][rt][c], 0, 0, 0);
                }
            }
        }
    }

    // ---- epilogue (fp32) ----
#pragma unroll
    for (int rt = 0; rt < 4; ++rt) {
#pragma unroll
        for (int i = 0; i < 4; ++i) {
            int row = row0 + rt * 16 + quad * 4 + i;
            if (row < M) {
                float dg = (float)deg[row];
#pragma unroll
                for (int c = 0; c < 2; ++c) {
                    int col = wave * 32 + c * 16 + ln;
                    float p1 = acc[0][rt][c][i] + B1[col];
                    float h2 = 2.f * (acc[1][rt][c][i] + dg * B2[col]);
                    float z  = 2.f * (acc[2][rt][c][i] + dg * (B3[col] + B4[col]));
                    float g = 1.f / (1.f + __expf(-z));
                    out[(size_t)row * 128 + col] = g * h2 + p1;
                }
            }
        }
    }
}

extern "C" void kernel_launch(void* const* d_in, const int* in_sizes, int n_in,
                              void* d_out, int out_size, void* d_ws, size_t ws_size,
                              hipStream_t stream) {
    const float* x  = (const float*)d_in[0];
    const int* eidx = (const int*)d_in[1];
    const float* W1 = (const float*)d_in[2];
    const float* B1 = (const float*)d_in[3];
    const float* W2 = (const float*)d_in[4];
    const float* B2 = (const float*)d_in[5];
    const float* W3 = (const float*)d_in[6];
    const float* B3 = (const float*)d_in[7];
    const float* W4 = (const float*)d_in[8];
    const float* B4 = (const float*)d_in[9];
    float* out      = (float*)d_out;

    const int M  = in_sizes[0] / 128;   // 100000 nodes
    const int NE = in_sizes[1] / 2;     // 1600000 edges
    const int* src = eidx;
    const int* dst = eidx + NE;

    // workspace needs: full path uses xb (bf16 copy of x); fallback gathers fp32 x.
    const size_t xb_bytes = (size_t)M * 128 * 2;
    const size_t fixed =
        ((size_t)M * 128 * 2 + 127 & ~(size_t)127) +      // gb
        ((size_t)3 * 16384 * 2 + 127 & ~(size_t)127) +    // Wb
        3 * (((size_t)(M + 1) * 4 + 127) & ~(size_t)127) + // deg, offs, cursor
        (((size_t)NE * 4 + 127) & ~(size_t)127);          // csr
    const bool full = ws_size >= fixed + xb_bytes + 1024;

    char* ws = (char*)d_ws;
    size_t off = 0;
    auto take = [&](size_t bytes) -> char* {
        char* p = ws + off;
        off = (off + bytes + 127) & ~(size_t)127;
        return p;
    };
    unsigned short* xb = full ? (unsigned short*)take(xb_bytes) : nullptr;
    unsigned short* gb = (unsigned short*)take((size_t)M * 128 * 2);
    unsigned short* Wb = (unsigned short*)take(3 * 16384 * 2);
    int* deg    = (int*)take((size_t)M * 4);
    int* offs   = (int*)take((size_t)(M + 1) * 4);
    int* cursor = (int*)take((size_t)M * 4);
    int* csr    = (int*)take((size_t)NE * 4);

    const int nx4 = full ? (M * 128 / 4) : 0;
    const int prep_elems = full ? (M * 32) : (M > 16384 ? M : 16384);
    const int ch = (M + 1023) / 1024;

    prep_kernel<<<(prep_elems + 255) / 256, 256, 0, stream>>>(
        x, W1, W2, W3, W4, full ? xb : gb, Wb, deg, M, nx4);
    hist_kernel<<<(NE + 255) / 256, 256, 0, stream>>>(dst, deg, NE);
    scan_kernel<<<1, 1024, 0, stream>>>(deg, offs, cursor, M, ch);
    fill_csr_kernel<<<(NE + 255) / 256, 256, 0, stream>>>(src, dst, cursor, csr, NE);
    if (full) {
        gather_kernel<true><<<(M + 3) / 4, 256, 0, stream>>>(xb, offs, csr, gb, M);
        gemm_kernel<true><<<(M + 63) / 64, 256, 0, stream>>>(
            xb, gb, deg, Wb, B1, B2, B3, B4, out, M);
    } else {
        gather_kernel<false><<<(M + 3) / 4, 256, 0, stream>>>(x, offs, csr, gb, M);
        gemm_kernel<false><<<(M + 63) / 64, 256, 0, stream>>>(
            x, gb, deg, Wb, B1, B2, B3, B4, out, M);
    }
}

// Round 5
// 417.571 us; speedup vs baseline: 1.7496x; 1.6101x over previous
//
#include <hip/hip_runtime.h>

// ---------- fp32 <-> bf16 helpers ----------
__device__ __forceinline__ float bf2f(unsigned short u) {
    union { unsigned int i; float f; } v;
    v.i = ((unsigned int)u) << 16;
    return v.f;
}
__device__ __forceinline__ unsigned short f2bf(float f) {
    union { float f; unsigned int i; } v;
    v.f = f;
    unsigned int x = v.i;
    return (unsigned short)((x + 0x7fffu + ((x >> 16) & 1u)) >> 16);
}

typedef short bf16x8 __attribute__((ext_vector_type(8)));
typedef float f32x4 __attribute__((ext_vector_type(4)));

// ---------- prep: zero deg, x fp32->bf16, W panels -> bf16 (W1, W2, W3+W4) ----------
__global__ void prep_kernel(const float* __restrict__ x,
                            const float* __restrict__ W1, const float* __restrict__ W2,
                            const float* __restrict__ W3, const float* __restrict__ W4,
                            unsigned short* __restrict__ xb, unsigned short* __restrict__ Wb,
                            int* __restrict__ deg, int M, int nx4)
{
    int i = blockIdx.x * 256 + threadIdx.x;
    if (i < nx4) {
        float4 v = ((const float4*)x)[i];
        unsigned lo = (unsigned)f2bf(v.x) | ((unsigned)f2bf(v.y) << 16);
        unsigned hi = (unsigned)f2bf(v.z) | ((unsigned)f2bf(v.w) << 16);
        uint2 p; p.x = lo; p.y = hi;
        *(uint2*)(xb + (size_t)i * 4) = p;
    }
    if (i < M) deg[i] = 0;
    if (i < 16384) {
        Wb[i]         = f2bf(W1[i]);
        Wb[16384 + i] = f2bf(W2[i]);
        Wb[32768 + i] = f2bf(W3[i] + W4[i]);
    }
}

// ---------- CSR build ----------
__global__ void hist_kernel(const int* __restrict__ dst, int* __restrict__ deg, int ne) {
    int e = blockIdx.x * blockDim.x + threadIdx.x;
    if (e < ne) atomicAdd(&deg[dst[e]], 1);
}

// coalesced 3-stage scan (98 blocks x 1024)
__global__ __launch_bounds__(1024) void scan_local_kernel(
    const int* __restrict__ deg, int* __restrict__ offs, int* __restrict__ bsum, int n)
{
    __shared__ int sh[1024];
    int t = threadIdx.x;
    int i = blockIdx.x * 1024 + t;
    int v = (i < n) ? deg[i] : 0;
    sh[t] = v;
    __syncthreads();
    int acc = v;
    for (int off = 1; off < 1024; off <<= 1) {
        int y = (t >= off) ? sh[t - off] : 0;
        __syncthreads();
        acc += y;
        sh[t] = acc;
        __syncthreads();
    }
    if (i < n) offs[i] = acc - v;  // exclusive within block
    if (t == 1023) bsum[blockIdx.x] = acc;
}

__global__ __launch_bounds__(128) void scan_totals_kernel(
    int* __restrict__ bsum, int* __restrict__ offs, int nb, int n)
{
    __shared__ int sh[128];
    int t = threadIdx.x;
    int v = (t < nb) ? bsum[t] : 0;
    sh[t] = v;
    __syncthreads();
    int acc = v;
    for (int off = 1; off < 128; off <<= 1) {
        int y = (t >= off) ? sh[t - off] : 0;
        __syncthreads();
        acc += y;
        sh[t] = acc;
        __syncthreads();
    }
    if (t < nb) bsum[t] = acc - v;   // exclusive block offsets, in place
    if (t == 127) offs[n] = acc;     // grand total == NE
}

__global__ __launch_bounds__(1024) void scan_finalize_kernel(
    int* __restrict__ offs, const int* __restrict__ bsum, int* __restrict__ cursor, int n)
{
    int i = blockIdx.x * 1024 + threadIdx.x;
    if (i < n) {
        int o = offs[i] + bsum[i >> 10];
        offs[i] = o;
        cursor[i] = o;
    }
}

__global__ void fill_csr_kernel(const int* __restrict__ src, const int* __restrict__ dst,
                                int* __restrict__ cursor, int* __restrict__ csr, int ne)
{
    int e = blockIdx.x * blockDim.x + threadIdx.x;
    if (e < ne) {
        int d = dst[e];
        int pos = atomicAdd(&cursor[d], 1);
        csr[pos] = src[e];
    }
}

// ---------- gather: one wave per node, 8-deep masked unroll, bf16 out ----------
template<bool BF16SRC>
__global__ __launch_bounds__(256) void gather_kernel(
    const void* __restrict__ xsrc, const int* __restrict__ offs,
    const int* __restrict__ csr, unsigned short* __restrict__ gb, int M)
{
    const int wave = threadIdx.x >> 6;
    const int lane = threadIdx.x & 63;
    const int node = blockIdx.x * 4 + wave;
    if (node >= M) return;
    const int e0 = offs[node];
    const int e1 = offs[node + 1];

    float s0 = 0.f, s1 = 0.f, t0 = 0.f, t1 = 0.f;
    for (int e = e0; e < e1; e += 8) {
        int id[8];
        float m[8];
#pragma unroll
        for (int j = 0; j < 8; ++j) {
            int ee = e + j;
            bool ok = ee < e1;
            id[j] = csr[ok ? ee : e1 - 1];
            m[j] = ok ? 1.f : 0.f;
        }
#pragma unroll
        for (int j = 0; j < 8; ++j) {
            float lo, hi;
            if (BF16SRC) {
                unsigned v = *(const unsigned*)((const unsigned short*)xsrc +
                                                (size_t)id[j] * 128 + lane * 2);
                lo = bf2f((unsigned short)(v & 0xffffu));
                hi = bf2f((unsigned short)(v >> 16));
            } else {
                float2 v = *(const float2*)((const float*)xsrc +
                                            (size_t)id[j] * 128 + lane * 2);
                lo = v.x;
                hi = v.y;
            }
            if (j & 1) { t0 += m[j] * lo; t1 += m[j] * hi; }
            else       { s0 += m[j] * lo; s1 += m[j] * hi; }
        }
    }
    unsigned pk = (unsigned)f2bf(s0 + t0) | ((unsigned)f2bf(s1 + t1) << 16);
    *(unsigned*)(gb + (size_t)node * 128 + lane * 2) = pk;
}

// ---------- 3-panel bf16 MFMA GEMM + fp32 epilogue ----------
// P1 = x*W1^T ; P2 = g*W2^T ; P34 = g*(W3+W4)^T
// out = sigmoid(2*(P34 + d*(b3+b4))) * (2*(P2 + d*b2)) + P1 + b1
template<bool XBF16>
__global__ __launch_bounds__(256) void gemm_kernel(
    const void* __restrict__ xsrc, const unsigned short* __restrict__ gb,
    const int* __restrict__ deg, const unsigned short* __restrict__ Wb,
    const float* __restrict__ B1, const float* __restrict__ B2,
    const float* __restrict__ B3, const float* __restrict__ B4,
    float* __restrict__ out, int M)
{
    __shared__ unsigned short x_lds[64 * 136];
    __shared__ unsigned short g_lds[64 * 136];

    const int t = threadIdx.x;
    const int wave = t >> 6;
    const int lane = t & 63;
    const int ln = lane & 15;
    const int quad = lane >> 4;
    const int row0 = blockIdx.x * 64;

    // ---- stage x tile ----
    if (XBF16) {
        const unsigned short* xb = (const unsigned short*)xsrc;
#pragma unroll
        for (int i = 0; i < 4; ++i) {
            int c = i * 256 + t;          // 1024 chunks of 16B
            int row = c >> 4;
            int koff = (c & 15) * 8;
            int grow = row0 + row;
            if (grow > M - 1) grow = M - 1;
            *(uint4*)&x_lds[row * 136 + koff] =
                *(const uint4*)(xb + (size_t)grow * 128 + koff);
        }
    } else {
        const float* xf = (const float*)xsrc;
#pragma unroll
        for (int i = 0; i < 8; ++i) {
            int c = i * 256 + t;          // 2048 chunks of float4
            int row = c >> 5;
            int koff = (c & 31) * 4;
            int grow = row0 + row;
            if (grow > M - 1) grow = M - 1;
            float4 v = *(const float4*)(xf + (size_t)grow * 128 + koff);
            unsigned p0 = (unsigned)f2bf(v.x) | ((unsigned)f2bf(v.y) << 16);
            unsigned p1 = (unsigned)f2bf(v.z) | ((unsigned)f2bf(v.w) << 16);
            *(unsigned*)&x_lds[row * 136 + koff]     = p0;
            *(unsigned*)&x_lds[row * 136 + koff + 2] = p1;
        }
    }
    // ---- stage g tile ----
#pragma unroll
    for (int i = 0; i < 4; ++i) {
        int c = i * 256 + t;
        int row = c >> 4;
        int koff = (c & 15) * 8;
        int grow = row0 + row;
        if (grow > M - 1) grow = M - 1;
        *(uint4*)&g_lds[row * 136 + koff] =
            *(const uint4*)(gb + (size_t)grow * 128 + koff);
    }
    __syncthreads();

    // ---- 3-panel GEMM: wave owns cols [wave*32, wave*32+32) ----
    f32x4 acc[3][4][2];
#pragma unroll
    for (int p = 0; p < 3; ++p)
#pragma unroll
        for (int rt = 0; rt < 4; ++rt)
#pragma unroll
            for (int c = 0; c < 2; ++c) {
                acc[p][rt][c][0] = 0.f; acc[p][rt][c][1] = 0.f;
                acc[p][rt][c][2] = 0.f; acc[p][rt][c][3] = 0.f;
            }

#pragma unroll
    for (int kk = 0; kk < 4; ++kk) {
        bf16x8 ax[4], ag[4];
#pragma unroll
        for (int rt = 0; rt < 4; ++rt) {
            ax[rt] = *(const bf16x8*)&x_lds[(rt * 16 + ln) * 136 + kk * 32 + quad * 8];
            ag[rt] = *(const bf16x8*)&g_lds[(rt * 16 + ln) * 136 + kk * 32 + quad * 8];
        }
#pragma unroll
        for (int p = 0; p < 3; ++p) {
#pragma unroll
            for (int c = 0; c < 2; ++c) {
                int col = wave * 32 + c * 16 + ln;
                bf16x8 bw = *(const bf16x8*)(Wb + (size_t)p * 16384 +
                                             (size_t)col * 128 + kk * 32 + quad * 8);
#pragma unroll
                for (int rt = 0; rt < 4; ++rt) {
                    acc[p][rt][c] = __builtin_amdgcn_mfma_f32_16x16x32_bf16(
                        (p == 0) ? ax[rt] : ag[rt], bw, acc[p][rt][c], 0, 0, 0);
                }
            }
        }
    }

    // ---- epilogue (fp32) ----
#pragma unroll
    for (int rt = 0; rt < 4; ++rt) {
#pragma unroll
        for (int i = 0; i < 4; ++i) {
            int row = row0 + rt * 16 + quad * 4 + i;
            if (row < M) {
                float dg = (float)deg[row];
#pragma unroll
                for (int c = 0; c < 2; ++c) {
                    int col = wave * 32 + c * 16 + ln;
                    float p1 = acc[0][rt][c][i] + B1[col];
                    float h2 = 2.f * (acc[1][rt][c][i] + dg * B2[col]);
                    float z  = 2.f * (acc[2][rt][c][i] + dg * (B3[col] + B4[col]));
                    float g = 1.f / (1.f + __expf(-z));
                    out[(size_t)row * 128 + col] = g * h2 + p1;
                }
            }
        }
    }
}

extern "C" void kernel_launch(void* const* d_in, const int* in_sizes, int n_in,
                              void* d_out, int out_size, void* d_ws, size_t ws_size,
                              hipStream_t stream) {
    const float* x  = (const float*)d_in[0];
    const int* eidx = (const int*)d_in[1];
    const float* W1 = (const float*)d_in[2];
    const float* B1 = (const float*)d_in[3];
    const float* W2 = (const float*)d_in[4];
    const float* B2 = (const float*)d_in[5];
    const float* W3 = (const float*)d_in[6];
    const float* B3 = (const float*)d_in[7];
    const float* W4 = (const float*)d_in[8];
    const float* B4 = (const float*)d_in[9];
    float* out      = (float*)d_out;

    const int M  = in_sizes[0] / 128;   // 100000 nodes
    const int NE = in_sizes[1] / 2;     // 1600000 edges
    const int* src = eidx;
    const int* dst = eidx + NE;

    // workspace needs: full path uses xb (bf16 copy of x); fallback gathers fp32 x.
    const size_t xb_bytes = (size_t)M * 128 * 2;
    const size_t fixed =
        (((size_t)M * 128 * 2 + 127) & ~(size_t)127) +     // gb
        (((size_t)3 * 16384 * 2 + 127) & ~(size_t)127) +   // Wb
        3 * (((size_t)(M + 1) * 4 + 127) & ~(size_t)127) + // deg, offs, cursor
        256 * 4 +                                          // bsum
        (((size_t)NE * 4 + 127) & ~(size_t)127);           // csr
    const bool full = ws_size >= fixed + xb_bytes + 1024;

    char* ws = (char*)d_ws;
    size_t off = 0;
    auto take = [&](size_t bytes) -> char* {
        char* p = ws + off;
        off = (off + bytes + 127) & ~(size_t)127;
        return p;
    };
    unsigned short* xb = full ? (unsigned short*)take(xb_bytes) : nullptr;
    unsigned short* gb = (unsigned short*)take((size_t)M * 128 * 2);
    unsigned short* Wb = (unsigned short*)take(3 * 16384 * 2);
    int* deg    = (int*)take((size_t)M * 4);
    int* offs   = (int*)take((size_t)(M + 1) * 4);
    int* cursor = (int*)take((size_t)M * 4);
    int* bsum   = (int*)take(256 * 4);
    int* csr    = (int*)take((size_t)NE * 4);

    const int nx4 = full ? (M * 128 / 4) : 0;
    const int prep_elems = full ? (M * 32) : (M > 16384 ? M : 16384);
    const int nbScan = (M + 1023) / 1024;

    prep_kernel<<<(prep_elems + 255) / 256, 256, 0, stream>>>(
        x, W1, W2, W3, W4, full ? xb : gb, Wb, deg, M, nx4);
    hist_kernel<<<(NE + 255) / 256, 256, 0, stream>>>(dst, deg, NE);
    scan_local_kernel<<<nbScan, 1024, 0, stream>>>(deg, offs, bsum, M);
    scan_totals_kernel<<<1, 128, 0, stream>>>(bsum, offs, nbScan, M);
    scan_finalize_kernel<<<nbScan, 1024, 0, stream>>>(offs, bsum, cursor, M);
    fill_csr_kernel<<<(NE + 255) / 256, 256, 0, stream>>>(src, dst, cursor, csr, NE);
    if (full) {
        gather_kernel<true><<<(M + 3) / 4, 256, 0, stream>>>(xb, offs, csr, gb, M);
        gemm_kernel<true><<<(M + 63) / 64, 256, 0, stream>>>(
            xb, gb, deg, Wb, B1, B2, B3, B4, out, M);
    } else {
        gather_kernel<false><<<(M + 3) / 4, 256, 0, stream>>>(x, offs, csr, gb, M);
        gemm_kernel<false><<<(M + 63) / 64, 256, 0, stream>>>(
            x, gb, deg, Wb, B1, B2, B3, B4, out, M);
    }
}